// Round 3
// baseline (274.255 us; speedup 1.0000x reference)
//
#include <hip/hip_runtime.h>
#include <math.h>

// Math reduction (EPS=1e-12 negligible at fp32):
//   gain = logit x exactly; base = sum softplus(x);
//   per_sample = base - (pos>0 ? pos : best), pos = sum_{m=1,x>0} x, best = max_{m=1} x.
//
// Layout: 16 lanes per row -> each wave processes 4 rows in ONE pass.
// 2048 blocks x 4 waves x 4 rows = 32768 rows exactly. 250 float4 per row
// split as idx = sub + 16*step, step 0..15 (step 15: sub<10 only).
// Chunks of 4 steps, double-buffered so loads stay in flight during compute.

constexpr int B = 32768;
constexpr int C = 1000;
constexpr int BLOCKS = 2048;
constexpr int THREADS = 256;
constexpr int WAVES_PER_BLOCK = 4;

__device__ __forceinline__ void elem_update(float x, float m,
                                            float& base, float& pos, float& best) {
    // softplus(x) = max(x,0) + log(1 + exp(-|x|)); x = -1e30 contributes 0
    float e  = __expf(-fabsf(x));
    float xp = fmaxf(x, 0.0f);
    base += xp + __logf(1.0f + e);
    pos  += m * xp;                       // m in {0,1}
    if (m != 0.0f) best = fmaxf(best, x);
}

__device__ __forceinline__ void vec_update(const float4& x, const float4& m,
                                           float& base, float& pos, float& best) {
    elem_update(x.x, m.x, base, pos, best);
    elem_update(x.y, m.y, base, pos, best);
    elem_update(x.z, m.z, base, pos, best);
    elem_update(x.w, m.w, base, pos, best);
}

__global__ __launch_bounds__(THREADS)
void row_loss_kernel(const float* __restrict__ X,
                     const float* __restrict__ M,
                     float* __restrict__ partial) {
    const int lane = threadIdx.x & 63;
    const int sub  = lane & 15;          // lane within 16-lane row group
    const int grp  = lane >> 4;          // which of the wave's 4 rows
    const int wave_in_block = threadIdx.x >> 6;
    const int gwave = blockIdx.x * WAVES_PER_BLOCK + wave_in_block;
    const int row   = gwave * 4 + grp;   // always < B

    const float4* x4 = reinterpret_cast<const float4*>(X + (size_t)row * C);
    const float4* m4 = reinterpret_cast<const float4*>(M + (size_t)row * C);

    float4 xA[4], mA[4], xB[4], mB[4];

    // chunk 0 -> A, chunk 1 -> B (16 float4 in flight)
    #pragma unroll
    for (int j = 0; j < 4; ++j) { int i = sub + 16*j;       xA[j] = x4[i]; mA[j] = m4[i]; }
    #pragma unroll
    for (int j = 0; j < 4; ++j) { int i = sub + 64 + 16*j;  xB[j] = x4[i]; mB[j] = m4[i]; }

    float base = 0.f, pos = 0.f, best = -INFINITY;

    // compute chunk0 while chunk1 in flight
    #pragma unroll
    for (int j = 0; j < 4; ++j) vec_update(xA[j], mA[j], base, pos, best);

    // prefetch chunk2 -> A
    #pragma unroll
    for (int j = 0; j < 4; ++j) { int i = sub + 128 + 16*j; xA[j] = x4[i]; mA[j] = m4[i]; }

    // compute chunk1 while chunk2 in flight
    #pragma unroll
    for (int j = 0; j < 4; ++j) vec_update(xB[j], mB[j], base, pos, best);

    // prefetch chunk3 (tail) -> B: steps 12..15, step 15 only sub<10
    #pragma unroll
    for (int j = 0; j < 3; ++j) { int i = sub + 192 + 16*j; xB[j] = x4[i]; mB[j] = m4[i]; }
    if (sub < 10) { xB[3] = x4[sub + 240]; mB[3] = m4[sub + 240]; }
    else {
        xB[3] = make_float4(-1e30f, -1e30f, -1e30f, -1e30f);  // softplus -> 0
        mB[3] = make_float4(0.f, 0.f, 0.f, 0.f);
    }

    // compute chunk2 while chunk3 in flight
    #pragma unroll
    for (int j = 0; j < 4; ++j) vec_update(xA[j], mA[j], base, pos, best);
    // compute chunk3
    #pragma unroll
    for (int j = 0; j < 4; ++j) vec_update(xB[j], mB[j], base, pos, best);

    // reduce within each 16-lane row group (4 rounds)
    #pragma unroll
    for (int off = 8; off > 0; off >>= 1) {
        base += __shfl_down(base, off, 16);
        pos  += __shfl_down(pos,  off, 16);
        best  = fmaxf(best, __shfl_down(best, off, 16));
    }

    // per-row result valid at sub==0 (lanes 0,16,32,48); sum the 4 rows
    float per = base - ((pos > 0.f) ? pos : best);
    float v = (sub == 0) ? per : 0.f;
    v += __shfl_down(v, 32, 64);
    v += __shfl_down(v, 16, 64);   // lane 0: sum of this wave's 4 rows

    __shared__ float s[WAVES_PER_BLOCK];
    if (lane == 0) s[wave_in_block] = v;
    __syncthreads();
    if (threadIdx.x == 0) {
        float t = 0.0f;
        #pragma unroll
        for (int i = 0; i < WAVES_PER_BLOCK; ++i) t += s[i];
        partial[blockIdx.x] = t;
    }
}

__global__ __launch_bounds__(256)
void finalize_kernel(const float* __restrict__ partial, float* __restrict__ out) {
    double t = 0.0;
    for (int i = threadIdx.x; i < BLOCKS; i += 256) t += (double)partial[i];

    #pragma unroll
    for (int off = 32; off > 0; off >>= 1)
        t += __shfl_down(t, off, 64);

    __shared__ double s[4];
    const int lane = threadIdx.x & 63;
    const int w    = threadIdx.x >> 6;
    if (lane == 0) s[w] = t;
    __syncthreads();
    if (threadIdx.x == 0) {
        double r = s[0] + s[1] + s[2] + s[3];
        out[0] = (float)(r / (double)B);
    }
}

extern "C" void kernel_launch(void* const* d_in, const int* in_sizes, int n_in,
                              void* d_out, int out_size, void* d_ws, size_t ws_size,
                              hipStream_t stream) {
    const float* X  = (const float*)d_in[0];
    const float* M  = (const float*)d_in[1];
    float* out      = (float*)d_out;
    float* partial  = (float*)d_ws;   // BLOCKS floats = 8 KiB

    row_loss_kernel<<<BLOCKS, THREADS, 0, stream>>>(X, M, partial);
    finalize_kernel<<<1, 256, 0, stream>>>(partial, out);
}